// Round 10
// baseline (1361.326 us; speedup 1.0000x reference)
//
#include <hip/hip_runtime.h>

// ---------------------------------------------------------------------------
// ClassificationNCA — Round 9: R4 structure (wave-private, M=16/wave, all-n
// per wave) at finer grain: 128-thread blocks (2 waves, 2x16-cell tile),
// grid 2048 -> 8 blocks/CU, __launch_bounds__(128,6) (85-reg cap, 12-block
// residency). Layer3 fused by t-pairs -> LDS 8704 B; 2 barriers/step, each
// spanning only 2 waves. RTZ-hi activation split (lo compensates exactly).
// ---------------------------------------------------------------------------

#define ROTL32(x, d) (((x) << (d)) | ((x) >> (32 - (d))))

struct U2 { unsigned a, b; };

__host__ __device__ inline U2 tf2x32(unsigned k0, unsigned k1, unsigned c0, unsigned c1) {
  unsigned ks2 = k0 ^ k1 ^ 0x1BD11BDAu;
  unsigned x0 = c0 + k0;
  unsigned x1 = c1 + k1;
#define TF_ROUND4(r0, r1, r2, r3)                                              \
  x0 += x1; x1 = ROTL32(x1, r0); x1 ^= x0;                                     \
  x0 += x1; x1 = ROTL32(x1, r1); x1 ^= x0;                                     \
  x0 += x1; x1 = ROTL32(x1, r2); x1 ^= x0;                                     \
  x0 += x1; x1 = ROTL32(x1, r3); x1 ^= x0;
  TF_ROUND4(13, 15, 26, 6)
  x0 += k1;  x1 += ks2 + 1u;
  TF_ROUND4(17, 29, 16, 24)
  x0 += ks2; x1 += k0 + 2u;
  TF_ROUND4(13, 15, 26, 6)
  x0 += k0;  x1 += k1 + 3u;
  TF_ROUND4(17, 29, 16, 24)
  x0 += k1;  x1 += ks2 + 4u;
  TF_ROUND4(13, 15, 26, 6)
  x0 += ks2; x1 += k0 + 5u;
#undef TF_ROUND4
  U2 r; r.a = x0; r.b = x1; return r;
}

__device__ inline float erfinv_xla(float x) {
  float w = -log1pf(-x * x);
  float p;
  if (w < 5.0f) {
    w -= 2.5f;
    p = 2.81022636e-08f;
    p = fmaf(p, w, 3.43273939e-07f);
    p = fmaf(p, w, -3.5233877e-06f);
    p = fmaf(p, w, -4.39150654e-06f);
    p = fmaf(p, w, 0.00021858087f);
    p = fmaf(p, w, -0.00125372503f);
    p = fmaf(p, w, -0.00417768164f);
    p = fmaf(p, w, 0.246640727f);
    p = fmaf(p, w, 1.50140941f);
  } else {
    w = sqrtf(w) - 3.0f;
    p = -0.000200214257f;
    p = fmaf(p, w, 0.000100950558f);
    p = fmaf(p, w, 0.00134934322f);
    p = fmaf(p, w, -0.00367342844f);
    p = fmaf(p, w, 0.00573950773f);
    p = fmaf(p, w, -0.0076224613f);
    p = fmaf(p, w, 0.00943887047f);
    p = fmaf(p, w, 1.00167406f);
    p = fmaf(p, w, 2.83297682f);
  }
  return p * x;
}

__device__ inline float leaky(float v) { return v >= 0.0f ? v : 0.01f * v; }

typedef __attribute__((ext_vector_type(8))) short bf16x8;
typedef __attribute__((ext_vector_type(4))) float f32x4;

__host__ __device__ inline unsigned short bf16_rne(float x) {
  unsigned u = __float_as_uint(x);
  return (unsigned short)((u + 0x7FFFu + ((u >> 16) & 1u)) >> 16);
}

// Activation split: RTZ hi (1 shift) + RNE lo (compensates hi exactly).
__device__ inline void split2_rtz(float v, unsigned short& h, unsigned short& l) {
  unsigned u = __float_as_uint(v);
  h = (unsigned short)(u >> 16);
  l = bf16_rne(v - __uint_as_float(u & 0xFFFF0000u));
}

__device__ inline void split8(const float v[8], bf16x8& hi, bf16x8& lo) {
#pragma unroll
  for (int j = 0; j < 8; ++j) {
    unsigned short h, l;
    split2_rtz(v[j], h, l);
    hi[j] = (short)h;
    lo[j] = (short)l;
  }
}

// XOR swizzle for 64B rows: 4 x 16B groups, keyed on m&3.
__device__ inline int swz64(int m, int off) {
  int g = ((off >> 4) ^ m) & 3;
  return (g << 4) | (off & 15);
}

#define MFMA(a, b, c) __builtin_amdgcn_mfma_f32_16x16x32_bf16((a), (b), (c), 0, 0, 0)

// ---------------------------------------------------------------------------
// Weight prep (R4 layout): fragment-major packed B-tiles, 1 KB per tile.
// pw1 K-dim permuted to match direct perception fragments:
//   kc0: slot kq -> ps[kq]; kc1: slot kq -> px[kq], slot 29 -> t; kc2: py[kq].
// pw2: [nc(8)][t(8)][h,l], logical k. pw3: [kc(4)][f(4)], logical k.
// ---------------------------------------------------------------------------
__global__ void prep_weights(const float* __restrict__ w1, const float* __restrict__ w2,
                             const float* __restrict__ w3,
                             unsigned short* __restrict__ pw1,
                             unsigned short* __restrict__ pw2,
                             unsigned short* __restrict__ pw3) {
  int i = blockIdx.x * 256 + threadIdx.x;
  int e = i & 511, L = e >> 3, j = e & 7;
  int kq = (L >> 4) * 8 + j;   // k within 32-chunk
  int ln = L & 15;             // n within 16-tile
  if (i < 96 * 512) {          // pw1: [nc(8)][kc(3)][f(4)]
    int tile = i >> 9;
    int f = tile & 3, kc = (tile >> 2) % 3, nc = tile / 12;
    int n = nc * 32 + (f >> 1) * 16 + ln;
    int src;
    if (kc == 0)      src = (kq < 29) ? kq : -1;
    else if (kc == 1) src = (kq < 29) ? 29 + kq : ((kq == 29) ? 87 : -1);
    else              src = (kq < 29) ? 58 + kq : -1;
    float v = (src >= 0) ? w1[n * 88 + src] : 0.0f;
    unsigned short h = bf16_rne(v);
    pw1[i] = (f & 1) ? bf16_rne(v - __uint_as_float(((unsigned)h) << 16)) : h;
  }
  if (i < 128 * 512) {         // pw2: [nc(8)][t(8)][h,l]
    int tile = i >> 9;
    int hl = tile & 1, t = (tile >> 1) & 7, nc = tile >> 4;
    int n = t * 16 + ln;
    int k = nc * 32 + kq;
    float v = w2[n * 256 + k];
    unsigned short h = bf16_rne(v);
    pw2[i] = hl ? bf16_rne(v - __uint_as_float(((unsigned)h) << 16)) : h;
  }
  if (i < 16 * 512) {          // pw3: [kc(4)][f(4)]
    int tile = i >> 9;
    int f = tile & 3, kc = tile >> 2;
    int n = (f >> 1) * 16 + ln;
    int k = kc * 32 + kq;
    float v = (n < 29) ? w3[n * 128 + k] : 0.0f;
    unsigned short h = bf16_rne(v);
    pw3[i] = (f & 1) ? bf16_rne(v - __uint_as_float(((unsigned)h) << 16)) : h;
  }
}

// ---------------------------------------------------------------------------
__global__ void init_state(const float* __restrict__ x, float* __restrict__ s0,
                           float* __restrict__ s1, unsigned hk0, unsigned hk1) {
  int idx = blockIdx.x * 256 + threadIdx.x;
  if (idx >= 16 * 29 * 4096) return;
  int pix = idx & 4095;
  int c = (idx >> 12) % 29;
  int b = idx / (4096 * 29);
  float v;
  if (c < 3) {
    v = x[(b * 3 + c) * 4096 + pix];
    s1[idx] = v;
  } else if (c < 19) {
    int ch = c - 3;
    int i = (b * 16 + ch) * 4096 + pix;
    const int half = 131072;
    unsigned bits;
    if (i < half) bits = tf2x32(hk0, hk1, (unsigned)i, (unsigned)(i + half)).a;
    else          bits = tf2x32(hk0, hk1, (unsigned)(i - half), (unsigned)i).b;
    float f = __uint_as_float((bits >> 9) | 0x3F800000u) - 1.0f;
    const float lo = -0x1.fffffep-1f;
    float u = fmaxf(lo, fmaf(f, 2.0f, lo));
    v = fmaf(0.225f, 1.41421356237f * erfinv_xla(u), 0.5f);
  } else {
    v = 0.0f;
  }
  s0[idx] = v;
}

// ---------------------------------------------------------------------------
// One NCA step. Block = 128 threads = 2 waves; tile = 2 rows x 16 cols = 32
// cells; wave w owns cell row w (m-strip [16w, 16w+16)) for ALL layers ->
// h1c/h2c rows wave-private, zero barriers in the MLP. LDS = 8704 B:
//   h1c hi [32][64B] at 0, lo at 2048; h2c hi [32][64B] at 4096, lo at 6144.
//   sS halo f32[29][73] (4 rows x 18 + pad) overlays [0, 8468) in phase 1.
// 2 barriers/step (after halo, after A1-frag build).
// ---------------------------------------------------------------------------
__global__ __launch_bounds__(128, 6) void nca_step(
    const float* __restrict__ sin_, float* __restrict__ sout,
    const unsigned short* __restrict__ pw1, const float* __restrict__ b1,
    const unsigned short* __restrict__ pw2, const unsigned short* __restrict__ pw3,
    float tval, unsigned fk0, unsigned fk1) {
  __shared__ __align__(16) char lds[8704];
  char* h1h = lds;
  char* h1l = lds + 2048;
  char* h2h = lds + 4096;
  char* h2l = lds + 6144;
  float* sS = (float*)lds;   // [29][73] f32, phase 1 only

  const int tid = threadIdx.x;
  const int w = tid >> 6;          // wave id = cell row within tile
  const int L = tid & 63;
  const int lane16 = L & 15;
  const int quad = L >> 4;
  const int b = blockIdx.z;
  const int ty0 = blockIdx.y * 2;
  const int tx0 = blockIdx.x * 16;
  const float* sb = sin_ + b * 29 * 4096;

  // --- P1: halo load (29 ch x 4 rows x 18 cols, zero-padded) ---
  for (int l = tid; l < 29 * 72; l += 128) {
    int c = l / 72;
    int rem = l - c * 72;
    int r = rem / 18;
    int x = rem - r * 18;
    int gy = ty0 - 1 + r, gx = tx0 - 1 + x;
    float v = 0.0f;
    if ((unsigned)gy < 64u && (unsigned)gx < 64u) v = sb[c * 4096 + gy * 64 + gx];
    sS[c * 73 + r * 18 + x] = v;
  }
  __syncthreads();  // B1

  // --- A1 fragments directly from halo (permuted K: ps | px,t | py) ---
  bf16x8 a1h[3], a1l[3];
  {
    float vps[8], vpx[8], vpy[8];
#pragma unroll
    for (int j = 0; j < 8; ++j) {
      int c = quad * 8 + j;
      int cc = (c < 29) ? c : 0;
      const float* S = sS + cc * 73 + (w + 1) * 18 + (lane16 + 1);
      float m00 = S[-19], m01 = S[-18], m02 = S[-17];
      float m10 = S[-1],  m11 = S[0],   m12 = S[1];
      float m20 = S[17],  m21 = S[18],  m22 = S[19];
      bool valid = (c < 29);
      vps[j] = valid ? m11 : 0.0f;
      float px = ((m02 - m00) + 2.0f * (m12 - m10) + (m22 - m20)) * 0.125f;
      float py = ((m20 + 2.0f * m21 + m22) - (m00 + 2.0f * m01 + m02)) * 0.125f;
      vpx[j] = valid ? px : ((c == 29) ? tval : 0.0f);
      vpy[j] = valid ? py : 0.0f;
    }
    split8(vps, a1h[0], a1l[0]);
    split8(vpx, a1h[1], a1l[1]);
    split8(vpy, a1h[2], a1l[2]);
  }
  __syncthreads();  // B2: sS dead -> h1c/h2c region usable

  const int L16 = L * 16;
  const int am = 16 * w + lane16;

  // --- fused layer1 -> layer2 over 8 n-chunks of 32 (wave-private h1c) ---
  f32x4 acc2[8];
#pragma unroll
  for (int t = 0; t < 8; ++t) acc2[t] = (f32x4){0.f, 0.f, 0.f, 0.f};

#pragma unroll 1
  for (int nc = 0; nc < 8; ++nc) {
    f32x4 c0 = (f32x4){0.f, 0.f, 0.f, 0.f};
    f32x4 c1 = (f32x4){0.f, 0.f, 0.f, 0.f};
#pragma unroll
    for (int kc = 0; kc < 3; ++kc) {
      const char* g = (const char*)pw1 + (nc * 3 + kc) * 4096;
      bf16x8 bh0 = *(const bf16x8*)(g + L16);
      bf16x8 bl0 = *(const bf16x8*)(g + 1024 + L16);
      bf16x8 bh1 = *(const bf16x8*)(g + 2048 + L16);
      bf16x8 bl1 = *(const bf16x8*)(g + 3072 + L16);
      c0 = MFMA(a1h[kc], bh0, c0);
      c0 = MFMA(a1h[kc], bl0, c0);
      c0 = MFMA(a1l[kc], bh0, c0);
      c1 = MFMA(a1h[kc], bh1, c1);
      c1 = MFMA(a1h[kc], bl1, c1);
      c1 = MFMA(a1l[kc], bh1, c1);
    }
    // bias + leaky + split -> h1c planes (wave-private rows)
    float bv0 = b1[nc * 32 + lane16];
    float bv1 = b1[nc * 32 + 16 + lane16];
#pragma unroll
    for (int r = 0; r < 4; ++r) {
      int m = 16 * w + quad * 4 + r;
      unsigned short h0, l0, h1v, l1;
      split2_rtz(leaky(c0[r] + bv0), h0, l0);
      split2_rtz(leaky(c1[r] + bv1), h1v, l1);
      *(unsigned short*)(h1h + m * 64 + swz64(m, lane16 * 2)) = h0;
      *(unsigned short*)(h1l + m * 64 + swz64(m, lane16 * 2)) = l0;
      *(unsigned short*)(h1h + m * 64 + swz64(m, 32 + lane16 * 2)) = h1v;
      *(unsigned short*)(h1l + m * 64 + swz64(m, 32 + lane16 * 2)) = l1;
    }
    // layer2 A-frags: direct bf16x8 reads (same wave's rows; lgkm-ordered)
    bf16x8 ah = *(const bf16x8*)(h1h + am * 64 + swz64(am, quad * 16));
    bf16x8 al = *(const bf16x8*)(h1l + am * 64 + swz64(am, quad * 16));
#pragma unroll
    for (int t = 0; t < 8; ++t) {
      const char* g = (const char*)pw2 + (nc * 8 + t) * 2048;
      bf16x8 bh = *(const bf16x8*)(g + L16);
      bf16x8 bl = *(const bf16x8*)(g + 1024 + L16);
      acc2[t] = MFMA(ah, bh, acc2[t]);
      acc2[t] = MFMA(ah, bl, acc2[t]);
      acc2[t] = MFMA(al, bh, acc2[t]);
    }
  }

  // --- layer3 fused by t-pairs (32-col h2 chunks, wave-private rows) ---
  f32x4 d0 = (f32x4){0.f, 0.f, 0.f, 0.f};
  f32x4 d1 = (f32x4){0.f, 0.f, 0.f, 0.f};
#pragma unroll 1
  for (int kc = 0; kc < 4; ++kc) {
#pragma unroll
    for (int tp = 0; tp < 2; ++tp) {
      f32x4 a = acc2[2 * kc + tp];
#pragma unroll
      for (int r = 0; r < 4; ++r) {
        int m = 16 * w + quad * 4 + r;
        unsigned short h, l;
        split2_rtz(leaky(a[r]), h, l);
        int off = (tp * 16 + lane16) * 2;
        *(unsigned short*)(h2h + m * 64 + swz64(m, off)) = h;
        *(unsigned short*)(h2l + m * 64 + swz64(m, off)) = l;
      }
    }
    bf16x8 ah = *(const bf16x8*)(h2h + am * 64 + swz64(am, quad * 16));
    bf16x8 al = *(const bf16x8*)(h2l + am * 64 + swz64(am, quad * 16));
    const char* g3 = (const char*)pw3 + kc * 4096;
    bf16x8 bh0 = *(const bf16x8*)(g3 + L16);
    bf16x8 bl0 = *(const bf16x8*)(g3 + 1024 + L16);
    bf16x8 bh1 = *(const bf16x8*)(g3 + 2048 + L16);
    bf16x8 bl1 = *(const bf16x8*)(g3 + 3072 + L16);
    d0 = MFMA(ah, bh0, d0);
    d0 = MFMA(ah, bl0, d0);
    d0 = MFMA(al, bh0, d0);
    d1 = MFMA(ah, bh1, d1);
    d1 = MFMA(ah, bl1, d1);
    d1 = MFMA(al, bh1, d1);
  }

  // --- fire mask in registers (lane's col = lane16, row = w) ---
  float fire;
  {
    int i = b * 4096 + (ty0 + w) * 64 + (tx0 + lane16);
    unsigned bits;
    if (i < 32768) bits = tf2x32(fk0, fk1, (unsigned)i, (unsigned)(i + 32768)).a;
    else           bits = tf2x32(fk0, fk1, (unsigned)(i - 32768), (unsigned)i).b;
    fire = (bits & 0x80000000u) ? 0.0f : 1.0f;
  }

  // --- epilogue: residual + fire (fire pulled via shuffle) ---
  float fr[4];
#pragma unroll
  for (int r = 0; r < 4; ++r) fr[r] = __shfl(fire, quad * 4 + r, 64);
  int gy = ty0 + w;
  int gxq = tx0 + quad * 4;
  float* ob = sout + b * 29 * 4096;
#pragma unroll
  for (int t3 = 0; t3 < 2; ++t3) {
    int c = t3 * 16 + lane16;
    if (c >= 3 && c <= 28) {
      float4 so = *(const float4*)(sb + c * 4096 + gy * 64 + gxq);
      f32x4 d = t3 ? d1 : d0;
      float4 o;
      o.x = fmaf(fr[0], d[0], so.x);
      o.y = fmaf(fr[1], d[1], so.y);
      o.z = fmaf(fr[2], d[2], so.z);
      o.w = fmaf(fr[3], d[3], so.w);
      *(float4*)(ob + c * 4096 + gy * 64 + gxq) = o;
    }
  }
}

// ---------------------------------------------------------------------------
__global__ __launch_bounds__(256) void finalize(const float* __restrict__ s,
                                                float* __restrict__ out) {
  __shared__ float red[256];
  __shared__ float ls[10];
  int b = blockIdx.x, tid = threadIdx.x;
  const float* sb = s + b * 29 * 4096;
  for (int o = 0; o < 10; ++o) {
    const float* ch = sb + (19 + o) * 4096;
    float p = 0.0f;
    for (int i = tid; i < 4096; i += 256) p += ch[i];
    red[tid] = p;
    __syncthreads();
    for (int st = 128; st > 0; st >>= 1) {
      if (tid < st) red[tid] += red[tid + st];
      __syncthreads();
    }
    if (tid == 0) ls[o] = red[0] * (1.0f / 4096.0f);
    __syncthreads();
  }
  if (tid == 0) {
    float m = ls[0];
    for (int o = 1; o < 10; ++o) m = fmaxf(m, ls[o]);
    float e[10], sum = 0.0f;
    for (int o = 0; o < 10; ++o) { e[o] = expf(ls[o] - m); sum += e[o]; }
    for (int o = 0; o < 10; ++o) out[b * 10 + o] = e[o] / sum;
  }
}

// ---------------------------------------------------------------------------
extern "C" void kernel_launch(void* const* d_in, const int* in_sizes, int n_in,
                              void* d_out, int out_size, void* d_ws, size_t ws_size,
                              hipStream_t stream) {
  const float* x  = (const float*)d_in[0];
  const float* w1 = (const float*)d_in[1];
  const float* b1 = (const float*)d_in[2];
  const float* w2 = (const float*)d_in[3];
  const float* w3 = (const float*)d_in[4];
  const int STEPS = 20;  // setup_inputs() fixes steps=20

  const size_t STATE = (size_t)16 * 29 * 4096;
  float* ws = (float*)d_ws;
  float* s0 = ws;
  float* s1 = ws + STATE;
  unsigned short* pw1 = (unsigned short*)(ws + 2 * STATE);  // 96*512 shorts
  unsigned short* pw2 = pw1 + 96 * 512;                      // 128*512
  unsigned short* pw3 = pw2 + 128 * 512;                     // 16*512
  (void)ws_size; (void)n_in; (void)in_sizes; (void)out_size;

  prep_weights<<<256, 256, 0, stream>>>(w1, w2, w3, pw1, pw2, pw3);

  U2 hk = tf2x32(0u, 42u, 0u, 10000u);  // fold_in(key(42), 10000)
  init_state<<<(16 * 29 * 4096 + 255) / 256, 256, 0, stream>>>(x, s0, s1, hk.a, hk.b);

  for (int s = 0; s < STEPS; ++s) {
    U2 fk = tf2x32(0u, 42u, 0u, (unsigned)s);  // fold_in(key(42), step)
    float tval = (float)s / 100.0f;
    const float* in = (s & 1) ? s1 : s0;
    float* out = (s & 1) ? s0 : s1;
    dim3 grid(4, 32, 16);  // 16-wide x 2-tall tiles, batch
    nca_step<<<grid, 128, 0, stream>>>(in, out, pw1, b1, pw2, pw3, tval, fk.a, fk.b);
  }
  finalize<<<16, 256, 0, stream>>>(s0, (float*)d_out);
}